// Round 9
// baseline (126.386 us; speedup 1.0000x reference)
//
#include <hip/hip_runtime.h>
#include <cstdint>
#include <cmath>

#define DD 2048
#define NROW 4096
#define BHALF 2048
#define NT 64              // K-tiles of 32

typedef __attribute__((ext_vector_type(8))) __bf16 bf16x8;
typedef __attribute__((ext_vector_type(4))) float f32x4;

typedef __attribute__((address_space(1))) const void* as1cv;
typedef __attribute__((address_space(3))) void* as3v;

__device__ __forceinline__ void gload_lds16(const void* g, void* l) {
  __builtin_amdgcn_global_load_lds((as1cv)g, (as3v)l, 16, 0, 0);
}

__device__ __forceinline__ float fixv(float x) {
  if (isnan(x)) return 0.0f;
  if (isinf(x)) return x > 0.0f ? 10000.0f : -10000.0f;
  return x;
}

// ---- workspace layout (bytes) ----
constexpr size_t TB_OFF     = 0;                              // bf16 total [4096][2048]
constexpr size_t SQ_OFF     = (size_t)NROW * DD * 2;          // f32[4096]
constexpr size_t CS_SRC_OFF = SQ_OFF + NROW * 4;              // f32[2048]
constexpr size_t CS_TGT_OFF = CS_SRC_OFF + DD * 4;            // f32[2048]
constexpr size_t ACC_OFF    = CS_TGT_OFF + DD * 4;            // f64[4]
constexpr size_t SCAL_OFF   = ACC_OFF + 4 * 8;                // f32 lin

// Pass 1: nan_to_num, bf16 convert, row sum-of-squares, column sums.
__global__ __launch_bounds__(512) void k_prep(const float* __restrict__ src,
                                              const float* __restrict__ tgt,
                                              __bf16* __restrict__ Tb,
                                              float* __restrict__ sq,
                                              float* __restrict__ cs_src,
                                              float* __restrict__ cs_tgt) {
  int b = blockIdx.x;
  int t = threadIdx.x, l = t & 63, w = t >> 6;
  int half = t >> 8;             // 0: rows 0-7, 1: rows 8-15
  int tc = t & 255;              // col group (8 cols each)
  int row0 = b * 16;
  const float* base = (b < 128) ? (src + (size_t)row0 * DD)
                                : (tgt + (size_t)(row0 - BHALF) * DD);
  float* csp = (b < 128) ? cs_src : cs_tgt;
  int c0 = tc * 8;
  float cacc[8] = {0, 0, 0, 0, 0, 0, 0, 0};
  __shared__ float rbuf[8][8];
  __shared__ float cbuf[256][8];
#pragma unroll
  for (int r = 0; r < 8; ++r) {
    int row = half * 8 + r;
    const float4* p = (const float4*)(base + (size_t)row * DD + c0);
    float4 v0 = p[0], v1 = p[1];
    float x[8] = {v0.x, v0.y, v0.z, v0.w, v1.x, v1.y, v1.z, v1.w};
    bf16x8 bb;
    float a = 0.0f;
#pragma unroll
    for (int j = 0; j < 8; ++j) {
      float f = fixv(x[j]);
      a += f * f;
      cacc[j] += f;
      bb[j] = (__bf16)f;
    }
    *(bf16x8*)(Tb + (size_t)(row0 + row) * DD + c0) = bb;
    for (int o = 32; o; o >>= 1) a += __shfl_xor(a, o);
    if (l == 0) rbuf[w][r] = a;
  }
  if (half == 1) {
#pragma unroll
    for (int j = 0; j < 8; ++j) cbuf[tc][j] = cacc[j];
  }
  __syncthreads();
  if (half == 0) {
#pragma unroll
    for (int j = 0; j < 8; ++j) atomicAdd(&csp[c0 + j], cacc[j] + cbuf[tc][j]);
  }
  if (t < 16) {
    int h = t >> 3, rr = t & 7;
    sq[row0 + h * 8 + rr] = rbuf[h * 4 + 0][rr] + rbuf[h * 4 + 1][rr] +
                            rbuf[h * 4 + 2][rr] + rbuf[h * 4 + 3][rr];
  }
}

// Main: 128x256 tile, 8 waves (2M x 4N, per-wave 64x64), BK=32, 3-buffer
// rotation, ONE phase per K-tile. LDS 72 KiB -> 2 blocks/CU (16 waves): the
// cross-block wave overlap fills barrier/read stalls (m114 mechanism).
// Per tile: {aF4+bF4 ds_reads | stage A,B,B of t+2 into buf(t-1) | vmcnt(3) |
//            BAR | lgkm(0) | 16 MFMA | BAR}.
// vmcnt(3): outstanding after issue = {t+1:3, t+2:3} -> oldest 3 = tile t+1
// complete, one barrier before its reads. Stage target buf(t+2)%3 holds tile
// t-1, whose reads were lgkm-drained before BAR_b(t-1) < stage issue. Proven
// r8 staging/read swizzle pair (involution slot^((row16>>1)&3)).
__global__ __launch_bounds__(512, 4) void k_mmd(const __bf16* __restrict__ Tb,
                                                const float* __restrict__ sq,
                                                const float* __restrict__ cs_src,
                                                const float* __restrict__ cs_tgt,
                                                double* __restrict__ accd,
                                                float* __restrict__ scal) {
  // XCD-chunked bijective swizzle (512 % 8 == 0): each XCD gets 4 bi-rows.
  int lin = blockIdx.x;
  int t5 = (lin & 7) * 64 + (lin >> 3);
  int bi = t5 >> 4, bj = t5 & 15;   // bi: 32 x 128-row tiles, bj: 16 x 256-col

  // LDS: 3 bufs x (A 128x32 + B 256x32) bf16 = 3 x 24 KiB = 72 KiB
  __shared__ __attribute__((aligned(16))) __bf16 Sb[36864];

  int tid = threadIdx.x, l = tid & 63, w = tid >> 6;
  int wr = w >> 2, wc = w & 3;      // wave -> 64x64 output sub-tile
  int l15 = l & 15;

  f32x4 acc[4][4];
#pragma unroll
  for (int m = 0; m < 4; ++m)
#pragma unroll
    for (int n = 0; n < 4; ++n) acc[m][n] = (f32x4){0.0f, 0.0f, 0.0f, 0.0f};

  // staging: lane l -> row w*16+(l>>2), phys slot l&3, source col pre-swizzled
  int colsw = ((l & 3) ^ ((l >> 3) & 3)) * 8;
  size_t gA0 = (size_t)(bi * 128 + w * 16 + (l >> 2)) * DD + colsw;
  size_t gB0 = (size_t)(bj * 256 + w * 16 + (l >> 2)) * DD + colsw;
  int dW = w * 512;

#define CALLA(bf, T) gload_lds16(Tb + gA0 + (size_t)(T) * 32, \
                                 (void*)(Sb + (bf) + dW))
#define CALLB(bf, h, T) gload_lds16(Tb + gB0 + (size_t)(h) * 128 * DD + (size_t)(T) * 32, \
                                    (void*)(Sb + (bf) + 4096 + (h) * 4096 + dW))

  // LDS reads (swizzled): xk = (slot ^ ((l15>>1)&3))*8
  int xk = (((l >> 4) ^ ((l15 >> 1) & 3))) * 8;
  int aB = (wr * 64 + l15) * 32 + xk;               // + buf + m*512
  int bB = 4096 + (wc * 64 + l15) * 32 + xk;        // + buf + n*512

#define BAR()  __builtin_amdgcn_s_barrier()
#define SBAR() __builtin_amdgcn_sched_barrier(0)
#define LGKM0() asm volatile("s_waitcnt lgkmcnt(0)" ::: "memory")

  // prologue: tile0 -> buf0, tile1 -> buf1; wait tile0
  CALLA(0, 0); CALLB(0, 0, 0); CALLB(0, 1, 0);
  CALLA(12288, 1); CALLB(12288, 0, 1); CALLB(12288, 1, 1);
  asm volatile("s_waitcnt vmcnt(3)" ::: "memory");
  SBAR(); BAR(); SBAR();

  int selO = 0, stgO = 24576;   // buf t%3 and buf (t+2)%3 (element offsets)
#pragma unroll 1
  for (int t = 0; t < NT; ++t) {
    bf16x8 aF[4], bF[4];
#pragma unroll
    for (int m = 0; m < 4; ++m)
      aF[m] = *(const bf16x8*)(Sb + selO + aB + m * 512);
#pragma unroll
    for (int n = 0; n < 4; ++n)
      bF[n] = *(const bf16x8*)(Sb + selO + bB + n * 512);
    if (t < NT - 2) {
      CALLA(stgO, t + 2); CALLB(stgO, 0, t + 2); CALLB(stgO, 1, t + 2);
      asm volatile("s_waitcnt vmcnt(3)" ::: "memory");
    } else if (t == NT - 2) {
      asm volatile("s_waitcnt vmcnt(0)" ::: "memory");
    }
    SBAR(); BAR();
    LGKM0(); SBAR();
    __builtin_amdgcn_s_setprio(1);
#pragma unroll
    for (int m = 0; m < 4; ++m)
#pragma unroll
      for (int n = 0; n < 4; ++n)
        acc[m][n] = __builtin_amdgcn_mfma_f32_16x16x32_bf16(aF[m], bF[n], acc[m][n], 0, 0, 0);
    __builtin_amdgcn_s_setprio(0);
    SBAR(); BAR();
    // rotate: +1 mod 3 (in units of 12288 elements)
    selO = (selO == 24576) ? 0 : selO + 12288;
    stgO = (stgO == 24576) ? 0 : stgO + 12288;
  }

  // ---- in-block bandwidth (identical deterministic result in every block) ----
  float* red = (float*)Sb;
  float bw;
  {
    float ssq = 0.0f, s2 = 0.0f, dl = 0.0f;
#pragma unroll
    for (int k2 = 0; k2 < 8; ++k2) ssq += sq[tid + k2 * 512];
#pragma unroll
    for (int k2 = 0; k2 < 4; ++k2) {
      int c = tid + k2 * 512;
      float a = cs_src[c], b2 = cs_tgt[c];
      float s = a + b2;
      s2 += s * s;
      float d = (a - b2) * (1.0f / BHALF);
      dl += d * d;
    }
    for (int o = 32; o; o >>= 1) {
      ssq += __shfl_xor(ssq, o);
      s2  += __shfl_xor(s2, o);
      dl  += __shfl_xor(dl, o);
    }
    if (l == 0) { red[w] = ssq; red[8 + w] = s2; red[16 + w] = dl; }
    __syncthreads();
    double S = 0.0, Q = 0.0;
#pragma unroll
    for (int i = 0; i < 8; ++i) { S += red[i]; Q += red[8 + i]; }
    double meanL2 = 2.0 * S / (double)NROW - 2.0 * Q / ((double)NROW * (double)NROW);
    bw = (float)fmax(meanL2, 1e-6);
    if (tid == 0 && lin == 0) {
      double L = 0.0;
      for (int i = 0; i < 8; ++i) L += red[16 + i];
      scal[0] = (float)L;
    }
  }

  // ---- epilogue: L2 -> 5-kernel RBF sum ----
  float inv[5];
#pragma unroll
  for (int i = 0; i < 5; ++i) inv[i] = 1.0f / fmaxf(bw * (float)(1 << i), 1e-6f);

  float sum = 0.0f;
  int rbase = bi * 128 + wr * 64 + ((l >> 4) * 4);
  int cbase = bj * 256 + wc * 64 + l15;
#pragma unroll
  for (int m = 0; m < 4; ++m) {
    float4 sr = *(const float4*)(sq + rbase + m * 16);
    float sqr[4] = {sr.x, sr.y, sr.z, sr.w};
#pragma unroll
    for (int n = 0; n < 4; ++n) {
      float sc = sq[cbase + n * 16];
#pragma unroll
      for (int r = 0; r < 4; ++r) {
        float L2 = sqr[r] + sc - 2.0f * acc[m][n][r];
        L2 = fmaxf(L2, 0.0f);
#pragma unroll
        for (int i = 0; i < 5; ++i) {
          float s = fminf(L2 * inv[i], 50.0f);
          sum += __expf(-s);
        }
      }
    }
  }
  for (int o = 32; o; o >>= 1) sum += __shfl_xor(sum, o);
  if (l == 0) red[32 + w] = sum;
  __syncthreads();
  if (tid == 0) {
    double tot = 0.0;
    for (int i = 0; i < 8; ++i) tot += red[32 + i];
    int cat = (bi >= 16) * 2 + (bj >= 8);
    atomicAdd(accd + cat, tot);
  }
}

__global__ void k_final(const double* __restrict__ accd,
                        const float* __restrict__ scal,
                        float* __restrict__ out) {
  double loss = (accd[0] + accd[3] - accd[1] - accd[2]) * (1.0 / 4194304.0);
  if (!isfinite(loss)) loss = (double)scal[0];
  out[0] = (float)loss;
}

extern "C" void kernel_launch(void* const* d_in, const int* in_sizes, int n_in,
                              void* d_out, int out_size, void* d_ws, size_t ws_size,
                              hipStream_t stream) {
  const float* src = (const float*)d_in[0];
  const float* tgt = (const float*)d_in[1];
  char* ws = (char*)d_ws;
  __bf16* Tb     = (__bf16*)(ws + TB_OFF);
  float*  sq     = (float*)(ws + SQ_OFF);
  float*  cs_src = (float*)(ws + CS_SRC_OFF);
  float*  cs_tgt = (float*)(ws + CS_TGT_OFF);
  double* accd   = (double*)(ws + ACC_OFF);
  float*  scal   = (float*)(ws + SCAL_OFF);

  // zero colsums + category accumulators (ws is NOT re-poisoned between replays)
  hipMemsetAsync(ws + CS_SRC_OFF, 0, (DD * 4) * 2 + 4 * 8, stream);

  k_prep<<<256, 512, 0, stream>>>(src, tgt, Tb, sq, cs_src, cs_tgt);
  k_mmd<<<512, 512, 0, stream>>>(Tb, sq, cs_src, cs_tgt, accd, scal);
  k_final<<<1, 1, 0, stream>>>(accd, scal, (float*)d_out);
}

// Round 10
// 114.221 us; speedup vs baseline: 1.1065x; 1.1065x over previous
//
#include <hip/hip_runtime.h>
#include <cstdint>
#include <cmath>

#define DD 2048
#define NROW 4096
#define BHALF 2048
#define NT 64              // K-tiles of 32
#define NB 32              // 4096/128 row tiles
#define NTRI 528           // NB*(NB+1)/2

typedef __attribute__((ext_vector_type(8))) __bf16 bf16x8;
typedef __attribute__((ext_vector_type(4))) float f32x4;

typedef __attribute__((address_space(1))) const void* as1cv;
typedef __attribute__((address_space(3))) void* as3v;

__device__ __forceinline__ void gload_lds16(const void* g, void* l) {
  __builtin_amdgcn_global_load_lds((as1cv)g, (as3v)l, 16, 0, 0);
}

__device__ __forceinline__ float fixv(float x) {
  if (isnan(x)) return 0.0f;
  if (isinf(x)) return x > 0.0f ? 10000.0f : -10000.0f;
  return x;
}

// ---- workspace layout (bytes) ----
constexpr size_t TB_OFF     = 0;                              // bf16 total [4096][2048]
constexpr size_t SQ_OFF     = (size_t)NROW * DD * 2;          // f32[4096]
constexpr size_t CS_SRC_OFF = SQ_OFF + NROW * 4;              // f32[2048]
constexpr size_t CS_TGT_OFF = CS_SRC_OFF + DD * 4;            // f32[2048]
constexpr size_t ACC_OFF    = CS_TGT_OFF + DD * 4;            // f64[4]
constexpr size_t SCAL_OFF   = ACC_OFF + 4 * 8;                // f32 lin

// Pass 1: nan_to_num, bf16 convert, row sum-of-squares, column sums.
__global__ __launch_bounds__(512) void k_prep(const float* __restrict__ src,
                                              const float* __restrict__ tgt,
                                              __bf16* __restrict__ Tb,
                                              float* __restrict__ sq,
                                              float* __restrict__ cs_src,
                                              float* __restrict__ cs_tgt) {
  int b = blockIdx.x;
  int t = threadIdx.x, l = t & 63, w = t >> 6;
  int half = t >> 8;             // 0: rows 0-7, 1: rows 8-15
  int tc = t & 255;              // col group (8 cols each)
  int row0 = b * 16;
  const float* base = (b < 128) ? (src + (size_t)row0 * DD)
                                : (tgt + (size_t)(row0 - BHALF) * DD);
  float* csp = (b < 128) ? cs_src : cs_tgt;
  int c0 = tc * 8;
  float cacc[8] = {0, 0, 0, 0, 0, 0, 0, 0};
  __shared__ float rbuf[8][8];
  __shared__ float cbuf[256][8];
#pragma unroll
  for (int r = 0; r < 8; ++r) {
    int row = half * 8 + r;
    const float4* p = (const float4*)(base + (size_t)row * DD + c0);
    float4 v0 = p[0], v1 = p[1];
    float x[8] = {v0.x, v0.y, v0.z, v0.w, v1.x, v1.y, v1.z, v1.w};
    bf16x8 bb;
    float a = 0.0f;
#pragma unroll
    for (int j = 0; j < 8; ++j) {
      float f = fixv(x[j]);
      a += f * f;
      cacc[j] += f;
      bb[j] = (__bf16)f;
    }
    *(bf16x8*)(Tb + (size_t)(row0 + row) * DD + c0) = bb;
    for (int o = 32; o; o >>= 1) a += __shfl_xor(a, o);
    if (l == 0) rbuf[w][r] = a;
  }
  if (half == 1) {
#pragma unroll
    for (int j = 0; j < 8; ++j) cbuf[tc][j] = cacc[j];
  }
  __syncthreads();
  if (half == 0) {
#pragma unroll
    for (int j = 0; j < 8; ++j) atomicAdd(&csp[c0 + j], cacc[j] + cbuf[tc][j]);
  }
  if (t < 16) {
    int h = t >> 3, rr = t & 7;
    sq[row0 + h * 8 + rr] = rbuf[h * 4 + 0][rr] + rbuf[h * 4 + 1][rr] +
                            rbuf[h * 4 + 2][rr] + rbuf[h * 4 + 3][rr];
  }
}

// Main: TRIANGLE grid (528 blocks, bi<=bj) of 128x128 tiles, 4 waves
// (2M x 2N, per-wave 64x64), BK=32, 3-buffer rotation (r8/r9-proven
// schedule). 48 KiB LDS -> 3 blocks/CU capacity; 528 blocks ~ 2.06/CU.
// Off-diagonal tiles credited to both (bi,bj) and (bj,bi) quadrant sums
// (r1/r2-proven). Per tile: {aF4+bF4 ds_reads | stage 4 calls of t+2 into
// buf(t-1) | vmcnt(4) | BAR | lgkm(0) | 16 MFMA | BAR}.
__global__ __launch_bounds__(256, 3) void k_mmd(const __bf16* __restrict__ Tb,
                                                const float* __restrict__ sq,
                                                const float* __restrict__ cs_src,
                                                const float* __restrict__ cs_tgt,
                                                double* __restrict__ accd,
                                                float* __restrict__ scal) {
  // XCD-chunked bijective swizzle (528 % 8 == 0), then triangle decode (r2-proven)
  int lin = blockIdx.x;
  int t5 = (lin & 7) * (NTRI / 8) + (lin >> 3);
  int bi = (int)((65.0 - sqrt(4225.0 - 8.0 * (double)t5)) * 0.5);
  if (bi > NB - 1) bi = NB - 1;
  while (32 * (bi + 1) - ((bi + 1) * bi) / 2 <= t5) ++bi;
  while (32 * bi - (bi * (bi - 1)) / 2 > t5) --bi;
  int bj = bi + (t5 - (32 * bi - (bi * (bi - 1)) / 2));

  // LDS: 3 bufs x (A 128x32 + B 128x32) bf16 = 3 x 16 KiB = 48 KiB
  __shared__ __attribute__((aligned(16))) __bf16 Sb[24576];

  int tid = threadIdx.x, l = tid & 63, w = tid >> 6;
  int wr = w >> 1, wc = w & 1;      // wave -> 64x64 output sub-tile
  int l15 = l & 15;

  f32x4 acc[4][4];
#pragma unroll
  for (int m = 0; m < 4; ++m)
#pragma unroll
    for (int n = 0; n < 4; ++n) acc[m][n] = (f32x4){0.0f, 0.0f, 0.0f, 0.0f};

  // staging: lane l -> row w*16+(l>>2), phys slot l&3, source col pre-swizzled
  // by involution slot^((row16>>1)&3) = slot^((l>>3)&3)  (r8/r9-proven pair)
  int colsw = ((l & 3) ^ ((l >> 3) & 3)) * 8;
  size_t gA0 = (size_t)(bi * 128 + w * 16 + (l >> 2)) * DD + colsw;
  size_t gB0 = (size_t)(bj * 128 + w * 16 + (l >> 2)) * DD + colsw;
  int dW = w * 512;                 // wave's 1KB chunk within a 64-row group

#define CALLA(bf, h, T) gload_lds16(Tb + gA0 + (size_t)(h) * 64 * DD + (size_t)(T) * 32, \
                                    (void*)(Sb + (bf) + (h) * 2048 + dW))
#define CALLB(bf, h, T) gload_lds16(Tb + gB0 + (size_t)(h) * 64 * DD + (size_t)(T) * 32, \
                                    (void*)(Sb + (bf) + 4096 + (h) * 2048 + dW))

  // LDS reads (swizzled): xk = (slot ^ ((l15>>1)&3))*8
  int xk = (((l >> 4) ^ ((l15 >> 1) & 3))) * 8;
  int aB = (wr * 64 + l15) * 32 + xk;               // + buf + m*512
  int bB = 4096 + (wc * 64 + l15) * 32 + xk;        // + buf + n*512

#define BAR()  __builtin_amdgcn_s_barrier()
#define SBAR() __builtin_amdgcn_sched_barrier(0)
#define LGKM0() asm volatile("s_waitcnt lgkmcnt(0)" ::: "memory")

  // prologue: tile0 -> buf0, tile1 -> buf1; wait tile0
  CALLA(0, 0, 0); CALLA(0, 1, 0); CALLB(0, 0, 0); CALLB(0, 1, 0);
  CALLA(8192, 0, 1); CALLA(8192, 1, 1); CALLB(8192, 0, 1); CALLB(8192, 1, 1);
  asm volatile("s_waitcnt vmcnt(4)" ::: "memory");
  SBAR(); BAR(); SBAR();

  int selO = 0, stgO = 16384;   // buf t%3 and buf (t+2)%3 (element offsets)
#pragma unroll 1
  for (int t = 0; t < NT; ++t) {
    bf16x8 aF[4], bF[4];
#pragma unroll
    for (int m = 0; m < 4; ++m)
      aF[m] = *(const bf16x8*)(Sb + selO + aB + m * 512);
#pragma unroll
    for (int n = 0; n < 4; ++n)
      bF[n] = *(const bf16x8*)(Sb + selO + bB + n * 512);
    if (t < NT - 2) {
      CALLA(stgO, 0, t + 2); CALLA(stgO, 1, t + 2);
      CALLB(stgO, 0, t + 2); CALLB(stgO, 1, t + 2);
      asm volatile("s_waitcnt vmcnt(4)" ::: "memory");
    } else if (t == NT - 2) {
      asm volatile("s_waitcnt vmcnt(0)" ::: "memory");
    }
    SBAR(); BAR();
    LGKM0(); SBAR();
    __builtin_amdgcn_s_setprio(1);
#pragma unroll
    for (int m = 0; m < 4; ++m)
#pragma unroll
      for (int n = 0; n < 4; ++n)
        acc[m][n] = __builtin_amdgcn_mfma_f32_16x16x32_bf16(aF[m], bF[n], acc[m][n], 0, 0, 0);
    __builtin_amdgcn_s_setprio(0);
    SBAR(); BAR();
    // rotate: +1 mod 3 (in units of 8192 elements = 16 KiB)
    selO = (selO == 16384) ? 0 : selO + 8192;
    stgO = (stgO == 16384) ? 0 : stgO + 8192;
  }

  // ---- in-block bandwidth (identical deterministic result in every block) ----
  float* red = (float*)Sb;
  float bw;
  {
    float ssq = 0.0f, s2 = 0.0f, dl = 0.0f;
#pragma unroll
    for (int k2 = 0; k2 < 16; ++k2) ssq += sq[tid + k2 * 256];
#pragma unroll
    for (int k2 = 0; k2 < 8; ++k2) {
      int c = tid + k2 * 256;
      float a = cs_src[c], b2 = cs_tgt[c];
      float s = a + b2;
      s2 += s * s;
      float d = (a - b2) * (1.0f / BHALF);
      dl += d * d;
    }
    for (int o = 32; o; o >>= 1) {
      ssq += __shfl_xor(ssq, o);
      s2  += __shfl_xor(s2, o);
      dl  += __shfl_xor(dl, o);
    }
    if (l == 0) { red[w] = ssq; red[8 + w] = s2; red[16 + w] = dl; }
    __syncthreads();
    double S = 0.0, Q = 0.0;
#pragma unroll
    for (int i = 0; i < 4; ++i) { S += red[i]; Q += red[8 + i]; }
    double meanL2 = 2.0 * S / (double)NROW - 2.0 * Q / ((double)NROW * (double)NROW);
    bw = (float)fmax(meanL2, 1e-6);
    if (tid == 0 && lin == 0) {
      double L = 0.0;
      for (int i = 0; i < 4; ++i) L += red[16 + i];
      scal[0] = (float)L;
    }
  }

  // ---- epilogue: L2 -> 5-kernel RBF sum; dual-credit symmetry ----
  float inv[5];
#pragma unroll
  for (int i = 0; i < 5; ++i) inv[i] = 1.0f / fmaxf(bw * (float)(1 << i), 1e-6f);

  float sum = 0.0f;
  int rbase = bi * 128 + wr * 64 + ((l >> 4) * 4);
  int cbase = bj * 128 + wc * 64 + l15;
#pragma unroll
  for (int m = 0; m < 4; ++m) {
    float4 sr = *(const float4*)(sq + rbase + m * 16);
    float sqr[4] = {sr.x, sr.y, sr.z, sr.w};
#pragma unroll
    for (int n = 0; n < 4; ++n) {
      float sc = sq[cbase + n * 16];
#pragma unroll
      for (int r = 0; r < 4; ++r) {
        float L2 = sqr[r] + sc - 2.0f * acc[m][n][r];
        L2 = fmaxf(L2, 0.0f);
#pragma unroll
        for (int i = 0; i < 5; ++i) {
          float s = fminf(L2 * inv[i], 50.0f);
          sum += __expf(-s);
        }
      }
    }
  }
  for (int o = 32; o; o >>= 1) sum += __shfl_xor(sum, o);
  if (l == 0) red[32 + w] = sum;
  __syncthreads();
  if (tid == 0) {
    double tot = 0.0;
    for (int i = 0; i < 4; ++i) tot += red[32 + i];
    int cat = (bi >= 16) * 2 + (bj >= 16);
    atomicAdd(accd + cat, tot);
    if (bi != bj) {
      int catT = (bj >= 16) * 2 + (bi >= 16);
      atomicAdd(accd + catT, tot);
    }
  }
}

__global__ void k_final(const double* __restrict__ accd,
                        const float* __restrict__ scal,
                        float* __restrict__ out) {
  double loss = (accd[0] + accd[3] - accd[1] - accd[2]) * (1.0 / 4194304.0);
  if (!isfinite(loss)) loss = (double)scal[0];
  out[0] = (float)loss;
}

extern "C" void kernel_launch(void* const* d_in, const int* in_sizes, int n_in,
                              void* d_out, int out_size, void* d_ws, size_t ws_size,
                              hipStream_t stream) {
  const float* src = (const float*)d_in[0];
  const float* tgt = (const float*)d_in[1];
  char* ws = (char*)d_ws;
  __bf16* Tb     = (__bf16*)(ws + TB_OFF);
  float*  sq     = (float*)(ws + SQ_OFF);
  float*  cs_src = (float*)(ws + CS_SRC_OFF);
  float*  cs_tgt = (float*)(ws + CS_TGT_OFF);
  double* accd   = (double*)(ws + ACC_OFF);
  float*  scal   = (float*)(ws + SCAL_OFF);

  // zero colsums + category accumulators (ws is NOT re-poisoned between replays)
  hipMemsetAsync(ws + CS_SRC_OFF, 0, (DD * 4) * 2 + 4 * 8, stream);

  k_prep<<<256, 512, 0, stream>>>(src, tgt, Tb, sq, cs_src, cs_tgt);
  k_mmd<<<NTRI, 256, 0, stream>>>(Tb, sq, cs_src, cs_tgt, accd, scal);
  k_final<<<1, 1, 0, stream>>>(accd, scal, (float*)d_out);
}